// Round 1
// baseline (241.924 us; speedup 1.0000x reference)
//
#include <hip/hip_runtime.h>
#include <hip/hip_bf16.h>

#define DIM   768
#define NH    12
#define HD    64
#define BB    2
#define SS    2048
#define QKVN  (3 * DIM)   // 2304
#define MM    (BB * SS)   // 4096

typedef __attribute__((ext_vector_type(8))) short bf16x8;
typedef __attribute__((ext_vector_type(4))) float f32x4;

__device__ __forceinline__ short f2bf(float f) {
    // round-to-nearest-even fp32 -> bf16
    unsigned int u = __float_as_uint(f);
    unsigned int r = (u + 0x7FFFu + ((u >> 16) & 1u)) >> 16;
    return (short)r;
}

// C[M][N] = A[M][K] @ B[N][K]^T + bias[N]; A,B fp32 in HBM, bf16 MFMA compute.
// Block = 256 thr = 4 waves (2x2), wave tile 64x64 (4x4 MFMA 16x16x32), block tile 128x128.
// M % 128 == 0, N % 128 == 0, K % 32 == 0 (all true here).
__global__ __launch_bounds__(256) void gemm_bt_kernel(
    const float* __restrict__ A, const float* __restrict__ Bm,
    const float* __restrict__ bias, float* __restrict__ C,
    int M, int N, int K)
{
    const int lane = threadIdx.x & 63;
    const int wid  = threadIdx.x >> 6;
    const int wr = wid >> 1, wc = wid & 1;
    const int row0 = blockIdx.y * 128 + wr * 64;
    const int col0 = blockIdx.x * 128 + wc * 64;
    const int l16  = lane & 15;   // A-row / B-col / C-col within 16-tile
    const int kg   = lane >> 4;   // k-group: k offset = kg*8

    f32x4 acc[4][4];
#pragma unroll
    for (int i = 0; i < 4; ++i)
#pragma unroll
        for (int j = 0; j < 4; ++j) acc[i][j] = (f32x4){0.f, 0.f, 0.f, 0.f};

    const float* aptr[4];
    const float* bptr[4];
#pragma unroll
    for (int t = 0; t < 4; ++t) {
        aptr[t] = A  + (size_t)(row0 + t * 16 + l16) * K + kg * 8;
        bptr[t] = Bm + (size_t)(col0 + t * 16 + l16) * K + kg * 8;
    }

    for (int k0 = 0; k0 < K; k0 += 32) {
        bf16x8 af[4], bfm[4];
#pragma unroll
        for (int t = 0; t < 4; ++t) {
            const float4* pa = (const float4*)(aptr[t] + k0);
            float4 alo = pa[0], ahi = pa[1];
            bf16x8 va;
            va[0] = f2bf(alo.x); va[1] = f2bf(alo.y); va[2] = f2bf(alo.z); va[3] = f2bf(alo.w);
            va[4] = f2bf(ahi.x); va[5] = f2bf(ahi.y); va[6] = f2bf(ahi.z); va[7] = f2bf(ahi.w);
            af[t] = va;
            const float4* pb = (const float4*)(bptr[t] + k0);
            float4 blo = pb[0], bhi = pb[1];
            bf16x8 vb;
            vb[0] = f2bf(blo.x); vb[1] = f2bf(blo.y); vb[2] = f2bf(blo.z); vb[3] = f2bf(blo.w);
            vb[4] = f2bf(bhi.x); vb[5] = f2bf(bhi.y); vb[6] = f2bf(bhi.z); vb[7] = f2bf(bhi.w);
            bfm[t] = vb;
        }
#pragma unroll
        for (int i = 0; i < 4; ++i)
#pragma unroll
            for (int j = 0; j < 4; ++j)
                acc[i][j] = __builtin_amdgcn_mfma_f32_16x16x32_bf16(
                    af[i], bfm[j], acc[i][j], 0, 0, 0);
    }

    // Epilogue: C/D layout col = lane&15, row = (lane>>4)*4 + reg (verified m89/m91)
#pragma unroll
    for (int j = 0; j < 4; ++j) {
        const int col = col0 + j * 16 + l16;
        const float bv = bias[col];
#pragma unroll
        for (int i = 0; i < 4; ++i) {
#pragma unroll
            for (int r = 0; r < 4; ++r) {
                const int row = row0 + i * 16 + kg * 4 + r;
                C[(size_t)row * N + col] = acc[i][j][r] + bv;
            }
        }
    }
}

// Sparse Fibonacci attention: one wave per (b,h,q); lane = d in [0,64).
// qkv layout: [b*S+s][3*DIM], q at col h*64+d, k at +DIM, v at +2*DIM.
// out: [b*S+s][DIM] at col h*64+d (== transpose(0,2,1,3).reshape).
__global__ __launch_bounds__(256) void fib_attn_kernel(
    const float* __restrict__ qkv, float* __restrict__ out)
{
    const int lane = threadIdx.x & 63;
    const int gi = blockIdx.x * 4 + (threadIdx.x >> 6);   // [0, B*H*S)
    const int s = gi % SS;
    const int t = gi / SS;
    const int h = t % NH;
    const int b = t / NH;

    const int coff = h * HD + lane;
    const size_t rowq = (size_t)(b * SS + s) * QKVN;
    const float q = qkv[rowq + coff];

    constexpr int NF = 17;
    const int fib[NF] = {0, 1, 2, 3, 5, 8, 13, 21, 34, 55, 89, 144,
                         233, 377, 610, 987, 1597};
    float sc[NF], vv[NF];
#pragma unroll
    for (int f = 0; f < NF; ++f) {
        const bool ok = (fib[f] <= s);
        float kv = 0.f, vval = 0.f;
        if (ok) {
            const size_t rk = (size_t)(b * SS + s - fib[f]) * QKVN;
            kv   = qkv[rk + DIM + coff];
            vval = qkv[rk + 2 * DIM + coff];
        }
        float part = q * kv;
#pragma unroll
        for (int off = 32; off; off >>= 1) part += __shfl_xor(part, off, 64);
        sc[f] = ok ? part * 0.125f : -1e30f;   // scale = 64^-0.5
        vv[f] = vval;
    }

    float mx = sc[0];
#pragma unroll
    for (int f = 1; f < NF; ++f) mx = fmaxf(mx, sc[f]);
    float den = 0.f, o = 0.f;
#pragma unroll
    for (int f = 0; f < NF; ++f) {
        const float p = __expf(sc[f] - mx);
        den += p;
        o   += p * vv[f];
    }
    out[(size_t)(b * SS + s) * DIM + coff] = o / den;
}

extern "C" void kernel_launch(void* const* d_in, const int* in_sizes, int n_in,
                              void* d_out, int out_size, void* d_ws, size_t ws_size,
                              hipStream_t stream)
{
    const float* x     = (const float*)d_in[0];
    const float* w_qkv = (const float*)d_in[1];
    const float* b_qkv = (const float*)d_in[2];
    const float* w_out = (const float*)d_in[3];
    const float* b_out = (const float*)d_in[4];
    // d_in[5] = mask — recomputed analytically (hardcoded fib offsets), unused.
    float* out = (float*)d_out;

    float* qkv  = (float*)d_ws;                                    // MM x QKVN fp32
    float* attn = (float*)((char*)d_ws + (size_t)MM * QKVN * 4);   // MM x DIM fp32

    dim3 blk(256, 1, 1);

    // GEMM1: qkv = x @ w_qkv^T + b_qkv   [4096 x 2304], K=768
    dim3 g1(QKVN / 128, MM / 128, 1);   // 18 x 32
    gemm_bt_kernel<<<g1, blk, 0, stream>>>(x, w_qkv, b_qkv, qkv, MM, QKVN, DIM);

    // Sparse attention: B*H*S waves, 4 waves/block
    dim3 g2((BB * NH * SS) / 4, 1, 1);  // 12288
    fib_attn_kernel<<<g2, blk, 0, stream>>>(qkv, attn);

    // GEMM2: out = attn @ w_out^T + b_out   [4096 x 768], K=768
    dim3 g3(DIM / 128, MM / 128, 1);    // 6 x 32
    gemm_bt_kernel<<<g3, blk, 0, stream>>>(attn, w_out, b_out, out, MM, DIM, DIM);
}

// Round 2
// 126.520 us; speedup vs baseline: 1.9121x; 1.9121x over previous
//
#include <hip/hip_runtime.h>
#include <hip/hip_bf16.h>

#define DIM   768
#define NH    12
#define HD    64
#define BB    2
#define SS    2048
#define QKVN  (3 * DIM)   // 2304
#define MM    (BB * SS)   // 4096

typedef __attribute__((ext_vector_type(8))) short bf16x8;
typedef __attribute__((ext_vector_type(8))) short short8;
typedef __attribute__((ext_vector_type(4))) float f32x4;

__device__ __forceinline__ short f2bf(float f) {
    unsigned int u = __float_as_uint(f);
    unsigned int r = (u + 0x7FFFu + ((u >> 16) & 1u)) >> 16;
    return (short)r;
}

__device__ __forceinline__ void gld16(const short* g, short* l) {
    __builtin_amdgcn_global_load_lds(
        (const __attribute__((address_space(1))) void*)g,
        (__attribute__((address_space(3))) void*)l, 16, 0, 0);
}

// fp32 -> bf16 conversion for x, w_qkv, w_out (one launch, 8 elems/thread)
__global__ __launch_bounds__(256) void conv_kernel(
    const float* __restrict__ x,  short* __restrict__ xb,
    const float* __restrict__ wq, short* __restrict__ wqb,
    const float* __restrict__ wo, short* __restrict__ wob)
{
    const int nx = (MM * DIM) / 8;     // 393216
    const int nq = (QKVN * DIM) / 8;   // 221184
    int i8 = blockIdx.x * 256 + threadIdx.x;
    const float* src; short* dst;
    if (i8 < nx)           { src = x;  dst = xb; }
    else if (i8 < nx + nq) { i8 -= nx; src = wq; dst = wqb; }
    else                   { i8 -= nx + nq; src = wo; dst = wob; }
    const float4* p = (const float4*)src + (size_t)i8 * 2;
    float4 a = p[0], b = p[1];
    short8 r;
    r[0] = f2bf(a.x); r[1] = f2bf(a.y); r[2] = f2bf(a.z); r[3] = f2bf(a.w);
    r[4] = f2bf(b.x); r[5] = f2bf(b.y); r[6] = f2bf(b.z); r[7] = f2bf(b.w);
    *((short8*)dst + i8) = r;
}

// C[M][N] = bf16(A[M][K]) @ bf16(B[N][K])^T + bias[N], C fp32.
// m97 structure: 128x128 block tile, BK=32, 4 waves (2x2), global_load_lds
// staging (linear LDS, wave base + lane*16), 8 ds_read_b128 + 16 MFMA / K-step.
__global__ __launch_bounds__(256) void gemm_bt_bf16_kernel(
    const short* __restrict__ A, const short* __restrict__ Bm,
    const float* __restrict__ bias, float* __restrict__ C,
    int M, int N, int K)
{
    __shared__ short lsA[128 * 32];
    __shared__ short lsB[128 * 32];

    const int t    = threadIdx.x;
    const int lane = t & 63;
    const int wid  = t >> 6;
    const int wr = wid >> 1, wc = wid & 1;
    const int l16  = lane & 15;
    const int kg   = lane >> 4;
    const int row0 = blockIdx.y * 128;
    const int col0 = blockIdx.x * 128;

    // staging: thread t covers tile row t/4 (issue0) and t/4+64 (issue1),
    // cols (t%4)*8 .. +8  -> flat LDS byte offset t*16 (= wid*1024 + lane*16)
    const int srow = t >> 2;
    const int scol = (t & 3) * 8;
    const short* As0 = A  + (size_t)(row0 + srow) * K + scol;
    const short* As1 = A  + (size_t)(row0 + 64 + srow) * K + scol;
    const short* Bs0 = Bm + (size_t)(col0 + srow) * K + scol;
    const short* Bs1 = Bm + (size_t)(col0 + 64 + srow) * K + scol;
    short* ldA0 = lsA + wid * 512;
    short* ldA1 = lsA + 2048 + wid * 512;
    short* ldB0 = lsB + wid * 512;
    short* ldB1 = lsB + 2048 + wid * 512;

    f32x4 acc[4][4];
#pragma unroll
    for (int i = 0; i < 4; ++i)
#pragma unroll
        for (int j = 0; j < 4; ++j) acc[i][j] = (f32x4){0.f, 0.f, 0.f, 0.f};

    for (int k0 = 0; k0 < K; k0 += 32) {
        gld16(As0 + k0, ldA0);
        gld16(As1 + k0, ldA1);
        gld16(Bs0 + k0, ldB0);
        gld16(Bs1 + k0, ldB1);
        __syncthreads();   // compiler drains vmcnt before s_barrier

        bf16x8 af[4], bfr[4];
#pragma unroll
        for (int i = 0; i < 4; ++i)
            af[i] = *(const bf16x8*)&lsA[(wr * 64 + i * 16 + l16) * 32 + kg * 8];
#pragma unroll
        for (int j = 0; j < 4; ++j)
            bfr[j] = *(const bf16x8*)&lsB[(wc * 64 + j * 16 + l16) * 32 + kg * 8];

#pragma unroll
        for (int i = 0; i < 4; ++i)
#pragma unroll
            for (int j = 0; j < 4; ++j)
                acc[i][j] = __builtin_amdgcn_mfma_f32_16x16x32_bf16(
                    af[i], bfr[j], acc[i][j], 0, 0, 0);
        __syncthreads();   // all reads done before next stage overwrites
    }

    // C/D layout: col = lane&15, row = (lane>>4)*4 + reg  (m89/m91)
#pragma unroll
    for (int j = 0; j < 4; ++j) {
        const int col = col0 + wc * 64 + j * 16 + l16;
        const float bv = bias[col];
#pragma unroll
        for (int i = 0; i < 4; ++i) {
            const int rbase = row0 + wr * 64 + i * 16 + kg * 4;
#pragma unroll
            for (int r = 0; r < 4; ++r)
                C[(size_t)(rbase + r) * N + col] = acc[i][j][r] + bv;
        }
    }
}

// Sparse Fibonacci attention: one wave per (b,h,q); lane = d. Writes bf16.
__global__ __launch_bounds__(256) void fib_attn_kernel(
    const float* __restrict__ qkv, short* __restrict__ out)
{
    const int lane = threadIdx.x & 63;
    const int gi = blockIdx.x * 4 + (threadIdx.x >> 6);   // [0, B*H*S)
    const int s = gi % SS;
    const int t = gi / SS;
    const int h = t % NH;
    const int b = t / NH;

    const int coff = h * HD + lane;
    const size_t rowq = (size_t)(b * SS + s) * QKVN;
    const float q = qkv[rowq + coff];

    constexpr int NF = 17;
    const int fib[NF] = {0, 1, 2, 3, 5, 8, 13, 21, 34, 55, 89, 144,
                         233, 377, 610, 987, 1597};
    float sc[NF], vv[NF];
#pragma unroll
    for (int f = 0; f < NF; ++f) {
        const bool ok = (fib[f] <= s);
        float kv = 0.f, vval = 0.f;
        if (ok) {
            const size_t rk = (size_t)(b * SS + s - fib[f]) * QKVN;
            kv   = qkv[rk + DIM + coff];
            vval = qkv[rk + 2 * DIM + coff];
        }
        float part = q * kv;
#pragma unroll
        for (int off = 32; off; off >>= 1) part += __shfl_xor(part, off, 64);
        sc[f] = ok ? part * 0.125f : -1e30f;
        vv[f] = vval;
    }

    float mx = sc[0];
#pragma unroll
    for (int f = 1; f < NF; ++f) mx = fmaxf(mx, sc[f]);
    float den = 0.f, o = 0.f;
#pragma unroll
    for (int f = 0; f < NF; ++f) {
        const float p = __expf(sc[f] - mx);
        den += p;
        o   += p * vv[f];
    }
    out[(size_t)(b * SS + s) * DIM + coff] = f2bf(o / den);
}

extern "C" void kernel_launch(void* const* d_in, const int* in_sizes, int n_in,
                              void* d_out, int out_size, void* d_ws, size_t ws_size,
                              hipStream_t stream)
{
    const float* x     = (const float*)d_in[0];
    const float* w_qkv = (const float*)d_in[1];
    const float* b_qkv = (const float*)d_in[2];
    const float* w_out = (const float*)d_in[3];
    const float* b_out = (const float*)d_in[4];
    float* out = (float*)d_out;

    // workspace layout (48.76 MB total; round-1 proved >= 50.3 MB available):
    //   [0)            qkv fp32   4096 x 2304            37,748,736 B
    //   [37748736)     buf1 bf16  4096 x 768 (x_bf, then attn_bf)  6,291,456 B
    //   [44040192)     wqkv_bf    2304 x 768              3,538,944 B
    //   [47579136)     wout_bf     768 x 768              1,179,648 B
    float* qkv   = (float*)d_ws;
    short* buf1  = (short*)((char*)d_ws + 37748736);
    short* wqkvb = (short*)((char*)d_ws + 44040192);
    short* woutb = (short*)((char*)d_ws + 47579136);

    dim3 blk(256, 1, 1);

    // fp32 -> bf16: x, w_qkv, w_out   (5,505,024 elems / 8 per thread)
    conv_kernel<<<dim3(2688, 1, 1), blk, 0, stream>>>(x, buf1, w_qkv, wqkvb, w_out, woutb);

    // GEMM1: qkv = x @ w_qkv^T + b_qkv   [4096 x 2304], K=768
    gemm_bt_bf16_kernel<<<dim3(QKVN / 128, MM / 128, 1), blk, 0, stream>>>(
        buf1, wqkvb, b_qkv, qkv, MM, QKVN, DIM);

    // Sparse attention (reads fp32 qkv, writes bf16 into buf1 — x_bf is dead now)
    fib_attn_kernel<<<dim3((BB * NH * SS) / 4, 1, 1), blk, 0, stream>>>(qkv, buf1);

    // GEMM2: out = attn @ w_out^T + b_out   [4096 x 768], K=768
    gemm_bt_bf16_kernel<<<dim3(DIM / 128, MM / 128, 1), blk, 0, stream>>>(
        buf1, woutb, b_out, out, MM, DIM, DIM);
}

// Round 3
// 115.958 us; speedup vs baseline: 2.0863x; 1.0911x over previous
//
#include <hip/hip_runtime.h>
#include <hip/hip_bf16.h>

#define DIM   768
#define NH    12
#define HD    64
#define BB    2
#define SS    2048
#define QKVN  (3 * DIM)   // 2304
#define MM    (BB * SS)   // 4096

typedef __attribute__((ext_vector_type(8))) short bf16x8;
typedef __attribute__((ext_vector_type(8))) short short8;
typedef __attribute__((ext_vector_type(4))) float f32x4;

__device__ __forceinline__ short f2bf(float f) {
    unsigned int u = __float_as_uint(f);
    unsigned int r = (u + 0x7FFFu + ((u >> 16) & 1u)) >> 16;
    return (short)r;
}
__device__ __forceinline__ float bf2f(short s) {
    return __uint_as_float((unsigned int)(unsigned short)s << 16);
}

__device__ __forceinline__ void gld16(const short* g, short* l) {
    __builtin_amdgcn_global_load_lds(
        (const __attribute__((address_space(1))) void*)g,
        (__attribute__((address_space(3))) void*)l, 16, 0, 0);
}

// fp32 -> bf16 conversion for x, w_qkv, w_out (one launch, 8 elems/thread)
__global__ __launch_bounds__(256) void conv_kernel(
    const float* __restrict__ x,  short* __restrict__ xb,
    const float* __restrict__ wq, short* __restrict__ wqb,
    const float* __restrict__ wo, short* __restrict__ wob)
{
    const int nx = (MM * DIM) / 8;     // 393216
    const int nq = (QKVN * DIM) / 8;   // 221184
    int i8 = blockIdx.x * 256 + threadIdx.x;
    const float* src; short* dst;
    if (i8 < nx)           { src = x;  dst = xb; }
    else if (i8 < nx + nq) { i8 -= nx; src = wq; dst = wqb; }
    else                   { i8 -= nx + nq; src = wo; dst = wob; }
    const float4* p = (const float4*)src + (size_t)i8 * 2;
    float4 a = p[0], b = p[1];
    short8 r;
    r[0] = f2bf(a.x); r[1] = f2bf(a.y); r[2] = f2bf(a.z); r[3] = f2bf(a.w);
    r[4] = f2bf(b.x); r[5] = f2bf(b.y); r[6] = f2bf(b.z); r[7] = f2bf(b.w);
    *((short8*)dst + i8) = r;
}

// GEMM1: qkvh = bf16(x_bf @ w_qkv^T + b_qkv) written head-split:
// qkvh[type][b][h][s][d] bf16, type in {q,k,v}. m97 structure, 128x128 tile.
__global__ __launch_bounds__(256) void gemm_qkv_kernel(
    const short* __restrict__ A, const short* __restrict__ Bm,
    const float* __restrict__ bias, short* __restrict__ qkvh)
{
    constexpr int K = DIM, N = QKVN;
    __shared__ short lsA[128 * 32];
    __shared__ short lsB[128 * 32];

    const int t    = threadIdx.x;
    const int lane = t & 63;
    const int wid  = t >> 6;
    const int wr = wid >> 1, wc = wid & 1;
    const int l16  = lane & 15;
    const int kg   = lane >> 4;
    const int row0 = blockIdx.y * 128;
    const int col0 = blockIdx.x * 128;

    const int srow = t >> 2;
    const int scol = (t & 3) * 8;
    const short* As0 = A  + (size_t)(row0 + srow) * K + scol;
    const short* As1 = A  + (size_t)(row0 + 64 + srow) * K + scol;
    const short* Bs0 = Bm + (size_t)(col0 + srow) * K + scol;
    const short* Bs1 = Bm + (size_t)(col0 + 64 + srow) * K + scol;
    short* ldA0 = lsA + wid * 512;
    short* ldA1 = lsA + 2048 + wid * 512;
    short* ldB0 = lsB + wid * 512;
    short* ldB1 = lsB + 2048 + wid * 512;

    f32x4 acc[4][4];
#pragma unroll
    for (int i = 0; i < 4; ++i)
#pragma unroll
        for (int j = 0; j < 4; ++j) acc[i][j] = (f32x4){0.f, 0.f, 0.f, 0.f};

    for (int k0 = 0; k0 < K; k0 += 32) {
        gld16(As0 + k0, ldA0);
        gld16(As1 + k0, ldA1);
        gld16(Bs0 + k0, ldB0);
        gld16(Bs1 + k0, ldB1);
        __syncthreads();

        bf16x8 af[4], bfr[4];
#pragma unroll
        for (int i = 0; i < 4; ++i)
            af[i] = *(const bf16x8*)&lsA[(wr * 64 + i * 16 + l16) * 32 + kg * 8];
#pragma unroll
        for (int j = 0; j < 4; ++j)
            bfr[j] = *(const bf16x8*)&lsB[(wc * 64 + j * 16 + l16) * 32 + kg * 8];

#pragma unroll
        for (int i = 0; i < 4; ++i)
#pragma unroll
            for (int j = 0; j < 4; ++j)
                acc[i][j] = __builtin_amdgcn_mfma_f32_16x16x32_bf16(
                    af[i], bfr[j], acc[i][j], 0, 0, 0);
        __syncthreads();
    }

    // epilogue: col c -> type=c/768, h=(c%768)/64, d=c%64; row m -> b=m/2048, s=m%2048
#pragma unroll
    for (int j = 0; j < 4; ++j) {
        const int col = col0 + wc * 64 + j * 16 + l16;
        const int ty = col / DIM;
        const int hh = (col % DIM) >> 6;
        const int dd = col & 63;
        const float bv = bias[col];
        const size_t cbase = ((size_t)(ty * BB * NH) * SS) * HD;  // type block
#pragma unroll
        for (int i = 0; i < 4; ++i) {
            const int rbase = row0 + wr * 64 + i * 16 + kg * 4;
#pragma unroll
            for (int r = 0; r < 4; ++r) {
                const int row = rbase + r;            // b*2048+s
                const int bq = row >> 11, sq = row & 2047;
                qkvh[cbase + (((size_t)(bq * NH + hh) * SS + sq) << 6) + dd] =
                    f2bf(acc[i][j][r] + bv);
            }
        }
    }
}

// GEMM2: C[M][N] = A_bf16 @ B_bf16^T + bias, C fp32. m97 structure.
__global__ __launch_bounds__(256) void gemm_bt_bf16_kernel(
    const short* __restrict__ A, const short* __restrict__ Bm,
    const float* __restrict__ bias, float* __restrict__ C,
    int M, int N, int K)
{
    __shared__ short lsA[128 * 32];
    __shared__ short lsB[128 * 32];

    const int t    = threadIdx.x;
    const int lane = t & 63;
    const int wid  = t >> 6;
    const int wr = wid >> 1, wc = wid & 1;
    const int l16  = lane & 15;
    const int kg   = lane >> 4;
    const int row0 = blockIdx.y * 128;
    const int col0 = blockIdx.x * 128;

    const int srow = t >> 2;
    const int scol = (t & 3) * 8;
    const short* As0 = A  + (size_t)(row0 + srow) * K + scol;
    const short* As1 = A  + (size_t)(row0 + 64 + srow) * K + scol;
    const short* Bs0 = Bm + (size_t)(col0 + srow) * K + scol;
    const short* Bs1 = Bm + (size_t)(col0 + 64 + srow) * K + scol;
    short* ldA0 = lsA + wid * 512;
    short* ldA1 = lsA + 2048 + wid * 512;
    short* ldB0 = lsB + wid * 512;
    short* ldB1 = lsB + 2048 + wid * 512;

    f32x4 acc[4][4];
#pragma unroll
    for (int i = 0; i < 4; ++i)
#pragma unroll
        for (int j = 0; j < 4; ++j) acc[i][j] = (f32x4){0.f, 0.f, 0.f, 0.f};

    for (int k0 = 0; k0 < K; k0 += 32) {
        gld16(As0 + k0, ldA0);
        gld16(As1 + k0, ldA1);
        gld16(Bs0 + k0, ldB0);
        gld16(Bs1 + k0, ldB1);
        __syncthreads();

        bf16x8 af[4], bfr[4];
#pragma unroll
        for (int i = 0; i < 4; ++i)
            af[i] = *(const bf16x8*)&lsA[(wr * 64 + i * 16 + l16) * 32 + kg * 8];
#pragma unroll
        for (int j = 0; j < 4; ++j)
            bfr[j] = *(const bf16x8*)&lsB[(wc * 64 + j * 16 + l16) * 32 + kg * 8];

#pragma unroll
        for (int i = 0; i < 4; ++i)
#pragma unroll
            for (int j = 0; j < 4; ++j)
                acc[i][j] = __builtin_amdgcn_mfma_f32_16x16x32_bf16(
                    af[i], bfr[j], acc[i][j], 0, 0, 0);
        __syncthreads();
    }

#pragma unroll
    for (int j = 0; j < 4; ++j) {
        const int col = col0 + wc * 64 + j * 16 + l16;
        const float bv = bias[col];
#pragma unroll
        for (int i = 0; i < 4; ++i) {
            const int rbase = row0 + wr * 64 + i * 16 + kg * 4;
#pragma unroll
            for (int r = 0; r < 4; ++r)
                C[(size_t)(rbase + r) * N + col] = acc[i][j][r] + bv;
        }
    }
}

// Sparse Fibonacci attention on head-split bf16 qkvh.
// Block = 4 waves = 4 consecutive q for one (b,h); lane = d.
// blockIdx mapping pins all 512 blocks of one (b,h) to one XCD:
//   idx = seq*8 + xcd ; bh = xcd + 8*(seq/512) ; q4 = seq%512 ; q = q4*4+wid
__global__ __launch_bounds__(256) void fib_attn_kernel(
    const short* __restrict__ qkvh, short* __restrict__ attn)
{
    const int idx  = blockIdx.x;
    const int xcd  = idx & 7;
    const int seq  = idx >> 3;
    const int bh   = xcd + 8 * (seq >> 9);     // [0, 24)
    const int s    = (seq & 511) * 4 + (threadIdx.x >> 6);
    const int lane = threadIdx.x & 63;
    const int b = bh / NH, h = bh % NH;

    constexpr size_t TYB = (size_t)BB * NH * SS * HD;   // one type block
    const size_t base = ((size_t)bh * SS) << 6;         // bh*S*64
    const float q = bf2f(qkvh[base + ((size_t)s << 6) + lane]);
    const short* Kp = qkvh + TYB     + base + lane;
    const short* Vp = qkvh + 2 * TYB + base + lane;

    constexpr int NF = 17;
    const int fib[NF] = {0, 1, 2, 3, 5, 8, 13, 21, 34, 55, 89, 144,
                         233, 377, 610, 987, 1597};
    float sc[NF], vv[NF];
#pragma unroll
    for (int f = 0; f < NF; ++f) {
        const bool ok = (fib[f] <= s);
        float kv = 0.f, vval = 0.f;
        if (ok) {
            const size_t ro = (size_t)(s - fib[f]) << 6;
            kv   = bf2f(Kp[ro]);
            vval = bf2f(Vp[ro]);
        }
        float part = q * kv;
#pragma unroll
        for (int off = 32; off; off >>= 1) part += __shfl_xor(part, off, 64);
        sc[f] = ok ? part * 0.125f : -1e30f;
        vv[f] = vval;
    }

    float mx = sc[0];
#pragma unroll
    for (int f = 1; f < NF; ++f) mx = fmaxf(mx, sc[f]);
    float den = 0.f, o = 0.f;
#pragma unroll
    for (int f = 0; f < NF; ++f) {
        const float p = __expf(sc[f] - mx);
        den += p;
        o   += p * vv[f];
    }
    attn[((size_t)(b * SS + s) * DIM) + h * HD + lane] = f2bf(o / den);
}

extern "C" void kernel_launch(void* const* d_in, const int* in_sizes, int n_in,
                              void* d_out, int out_size, void* d_ws, size_t ws_size,
                              hipStream_t stream)
{
    const float* x     = (const float*)d_in[0];
    const float* w_qkv = (const float*)d_in[1];
    const float* b_qkv = (const float*)d_in[2];
    const float* w_out = (const float*)d_in[3];
    const float* b_out = (const float*)d_in[4];
    float* out = (float*)d_out;

    // workspace (36.2 MB of >= 50.3 MB):
    //   [0)         qkvh   bf16 [3][2][12][2048][64]   18,874,368 B
    //   [18874368)  attn   bf16 [4096][768]             6,291,456 B
    //   [25165824)  x_bf   bf16 [4096][768]             6,291,456 B
    //   [31457280)  wqkvb  bf16 [2304][768]             3,538,944 B
    //   [34996224)  woutb  bf16 [768][768]              1,179,648 B
    short* qkvh  = (short*)d_ws;
    short* attnb = (short*)((char*)d_ws + 18874368);
    short* xb    = (short*)((char*)d_ws + 25165824);
    short* wqkvb = (short*)((char*)d_ws + 31457280);
    short* woutb = (short*)((char*)d_ws + 34996224);

    dim3 blk(256, 1, 1);

    conv_kernel<<<dim3(2688, 1, 1), blk, 0, stream>>>(x, xb, w_qkv, wqkvb, w_out, woutb);

    gemm_qkv_kernel<<<dim3(QKVN / 128, MM / 128, 1), blk, 0, stream>>>(
        xb, wqkvb, b_qkv, qkvh);

    fib_attn_kernel<<<dim3(12288, 1, 1), blk, 0, stream>>>(qkvh, attnb);

    gemm_bt_bf16_kernel<<<dim3(DIM / 128, MM / 128, 1), blk, 0, stream>>>(
        attnb, woutb, b_out, out, MM, DIM, DIM);
}

// Round 4
// 76.308 us; speedup vs baseline: 3.1703x; 1.5196x over previous
//
#include <hip/hip_runtime.h>
#include <hip/hip_bf16.h>

#define DIM   768
#define NH    12
#define HD    64
#define BB    2
#define SS    2048
#define QKVN  (3 * DIM)   // 2304
#define MM    (BB * SS)   // 4096

typedef __attribute__((ext_vector_type(8))) short bf16x8;
typedef __attribute__((ext_vector_type(8))) short short8;
typedef __attribute__((ext_vector_type(4))) float f32x4;

__device__ __forceinline__ short f2bf(float f) {
    unsigned int u = __float_as_uint(f);
    unsigned int r = (u + 0x7FFFu + ((u >> 16) & 1u)) >> 16;
    return (short)r;
}
__device__ __forceinline__ float bf2f(short s) {
    return __uint_as_float((unsigned int)(unsigned short)s << 16);
}

__device__ __forceinline__ void gld16(const short* g, short* l) {
    __builtin_amdgcn_global_load_lds(
        (const __attribute__((address_space(1))) void*)g,
        (__attribute__((address_space(3))) void*)l, 16, 0, 0);
}

// fp32 -> bf16 conversion for x, w_qkv, w_out (one launch, 8 elems/thread)
__global__ __launch_bounds__(256) void conv_kernel(
    const float* __restrict__ x,  short* __restrict__ xb,
    const float* __restrict__ wq, short* __restrict__ wqb,
    const float* __restrict__ wo, short* __restrict__ wob)
{
    const int nx = (MM * DIM) / 8;     // 393216
    const int nq = (QKVN * DIM) / 8;   // 221184
    int i8 = blockIdx.x * 256 + threadIdx.x;
    const float* src; short* dst;
    if (i8 < nx)           { src = x;  dst = xb; }
    else if (i8 < nx + nq) { i8 -= nx; src = wq; dst = wqb; }
    else                   { i8 -= nx + nq; src = wo; dst = wob; }
    const float4* p = (const float4*)src + (size_t)i8 * 2;
    float4 a = p[0], b = p[1];
    short8 r;
    r[0] = f2bf(a.x); r[1] = f2bf(a.y); r[2] = f2bf(a.z); r[3] = f2bf(a.w);
    r[4] = f2bf(b.x); r[5] = f2bf(b.y); r[6] = f2bf(b.z); r[7] = f2bf(b.w);
    *((short8*)dst + i8) = r;
}

// GEMM1: qkvh = bf16(x_bf @ w_qkv^T + b_qkv) written head-split:
// qkvh[type][b][h][s][d] bf16. m97 structure, 128x128 tile.
__global__ __launch_bounds__(256) void gemm_qkv_kernel(
    const short* __restrict__ A, const short* __restrict__ Bm,
    const float* __restrict__ bias, short* __restrict__ qkvh)
{
    constexpr int K = DIM;
    __shared__ short lsA[128 * 32];
    __shared__ short lsB[128 * 32];

    const int t    = threadIdx.x;
    const int lane = t & 63;
    const int wid  = t >> 6;
    const int wr = wid >> 1, wc = wid & 1;
    const int l16  = lane & 15;
    const int kg   = lane >> 4;
    const int row0 = blockIdx.y * 128;
    const int col0 = blockIdx.x * 128;

    const int srow = t >> 2;
    const int scol = (t & 3) * 8;
    const short* As0 = A  + (size_t)(row0 + srow) * K + scol;
    const short* As1 = A  + (size_t)(row0 + 64 + srow) * K + scol;
    const short* Bs0 = Bm + (size_t)(col0 + srow) * K + scol;
    const short* Bs1 = Bm + (size_t)(col0 + 64 + srow) * K + scol;
    short* ldA0 = lsA + wid * 512;
    short* ldA1 = lsA + 2048 + wid * 512;
    short* ldB0 = lsB + wid * 512;
    short* ldB1 = lsB + 2048 + wid * 512;

    f32x4 acc[4][4];
#pragma unroll
    for (int i = 0; i < 4; ++i)
#pragma unroll
        for (int j = 0; j < 4; ++j) acc[i][j] = (f32x4){0.f, 0.f, 0.f, 0.f};

    for (int k0 = 0; k0 < K; k0 += 32) {
        gld16(As0 + k0, ldA0);
        gld16(As1 + k0, ldA1);
        gld16(Bs0 + k0, ldB0);
        gld16(Bs1 + k0, ldB1);
        __syncthreads();

        bf16x8 af[4], bfr[4];
#pragma unroll
        for (int i = 0; i < 4; ++i)
            af[i] = *(const bf16x8*)&lsA[(wr * 64 + i * 16 + l16) * 32 + kg * 8];
#pragma unroll
        for (int j = 0; j < 4; ++j)
            bfr[j] = *(const bf16x8*)&lsB[(wc * 64 + j * 16 + l16) * 32 + kg * 8];

#pragma unroll
        for (int i = 0; i < 4; ++i)
#pragma unroll
            for (int j = 0; j < 4; ++j)
                acc[i][j] = __builtin_amdgcn_mfma_f32_16x16x32_bf16(
                    af[i], bfr[j], acc[i][j], 0, 0, 0);
        __syncthreads();
    }

    // epilogue: col c -> type=c/768, h=(c%768)/64, d=c%64; row m -> b=m/2048, s=m%2048
#pragma unroll
    for (int j = 0; j < 4; ++j) {
        const int col = col0 + wc * 64 + j * 16 + l16;
        const int ty = col / DIM;
        const int hh = (col % DIM) >> 6;
        const int dd = col & 63;
        const float bv = bias[col];
        const size_t cbase = ((size_t)(ty * BB * NH) * SS) * HD;
#pragma unroll
        for (int i = 0; i < 4; ++i) {
            const int rbase = row0 + wr * 64 + i * 16 + kg * 4;
#pragma unroll
            for (int r = 0; r < 4; ++r) {
                const int row = rbase + r;
                const int bq = row >> 11, sq = row & 2047;
                qkvh[cbase + (((size_t)(bq * NH + hh) * SS + sq) << 6) + dd] =
                    f2bf(acc[i][j][r] + bv);
            }
        }
    }
}

// GEMM2: C[M][N] = A_bf16 @ B_bf16^T + bias, C fp32. m97 structure.
__global__ __launch_bounds__(256) void gemm_bt_bf16_kernel(
    const short* __restrict__ A, const short* __restrict__ Bm,
    const float* __restrict__ bias, float* __restrict__ C,
    int M, int N, int K)
{
    __shared__ short lsA[128 * 32];
    __shared__ short lsB[128 * 32];

    const int t    = threadIdx.x;
    const int lane = t & 63;
    const int wid  = t >> 6;
    const int wr = wid >> 1, wc = wid & 1;
    const int l16  = lane & 15;
    const int kg   = lane >> 4;
    const int row0 = blockIdx.y * 128;
    const int col0 = blockIdx.x * 128;

    const int srow = t >> 2;
    const int scol = (t & 3) * 8;
    const short* As0 = A  + (size_t)(row0 + srow) * K + scol;
    const short* As1 = A  + (size_t)(row0 + 64 + srow) * K + scol;
    const short* Bs0 = Bm + (size_t)(col0 + srow) * K + scol;
    const short* Bs1 = Bm + (size_t)(col0 + 64 + srow) * K + scol;
    short* ldA0 = lsA + wid * 512;
    short* ldA1 = lsA + 2048 + wid * 512;
    short* ldB0 = lsB + wid * 512;
    short* ldB1 = lsB + 2048 + wid * 512;

    f32x4 acc[4][4];
#pragma unroll
    for (int i = 0; i < 4; ++i)
#pragma unroll
        for (int j = 0; j < 4; ++j) acc[i][j] = (f32x4){0.f, 0.f, 0.f, 0.f};

    for (int k0 = 0; k0 < K; k0 += 32) {
        gld16(As0 + k0, ldA0);
        gld16(As1 + k0, ldA1);
        gld16(Bs0 + k0, ldB0);
        gld16(Bs1 + k0, ldB1);
        __syncthreads();

        bf16x8 af[4], bfr[4];
#pragma unroll
        for (int i = 0; i < 4; ++i)
            af[i] = *(const bf16x8*)&lsA[(wr * 64 + i * 16 + l16) * 32 + kg * 8];
#pragma unroll
        for (int j = 0; j < 4; ++j)
            bfr[j] = *(const bf16x8*)&lsB[(wc * 64 + j * 16 + l16) * 32 + kg * 8];

#pragma unroll
        for (int i = 0; i < 4; ++i)
#pragma unroll
            for (int j = 0; j < 4; ++j)
                acc[i][j] = __builtin_amdgcn_mfma_f32_16x16x32_bf16(
                    af[i], bfr[j], acc[i][j], 0, 0, 0);
        __syncthreads();
    }

#pragma unroll
    for (int j = 0; j < 4; ++j) {
        const int col = col0 + wc * 64 + j * 16 + l16;
        const float bv = bias[col];
#pragma unroll
        for (int i = 0; i < 4; ++i) {
            const int rbase = row0 + wr * 64 + i * 16 + kg * 4;
#pragma unroll
            for (int r = 0; r < 4; ++r)
                C[(size_t)(rbase + r) * N + col] = acc[i][j][r] + bv;
        }
    }
}

// Sparse Fibonacci attention, wave = 16 queries.
// lane = (ql = lane>>2, c = lane&3); lane owns d-slice c*16..c*16+16.
// Dot reduce = 2-step shfl_xor within the 4-lane group.
// Pass 1: K-gather -> 17 scores in regs; softmax in regs; pass 2: V-gather.
// Block = 4 waves = 64 consecutive q of one (b,h); 768 blocks XCD-pinned.
__global__ __launch_bounds__(256) void fib_attn_kernel(
    const short* __restrict__ qkvh, short* __restrict__ attn)
{
    const int idx   = blockIdx.x;          // [0,768)
    const int x8    = idx & 7;
    const int j     = idx >> 3;            // [0,96)
    const int bh    = x8 + 8 * (j >> 5);   // [0,24) — all chunks of bh on one XCD
    const int chunk = j & 31;              // [0,32)
    const int wid   = threadIdx.x >> 6;
    const int lane  = threadIdx.x & 63;
    const int ql    = lane >> 2;
    const int c     = lane & 3;
    const int s     = chunk * 64 + wid * 16 + ql;
    const int b = bh / NH, h = bh % NH;

    constexpr size_t TYB = (size_t)BB * NH * SS * HD;
    const size_t base = ((size_t)bh * SS) << 6;
    const short* Kp = qkvh + TYB + base;
    const short* Vp = qkvh + 2 * TYB + base;

    // q fragment: 16 bf16 at [s][c*16..]
    float qv[16];
    {
        const bf16x8* p = (const bf16x8*)(qkvh + base + ((size_t)s << 6) + c * 16);
        bf16x8 lo = p[0], hi = p[1];
#pragma unroll
        for (int e = 0; e < 8; ++e) { qv[e] = bf2f(lo[e]); qv[8 + e] = bf2f(hi[e]); }
    }

    constexpr int NF = 17;
    const int fib[NF] = {0, 1, 2, 3, 5, 8, 13, 21, 34, 55, 89, 144,
                         233, 377, 610, 987, 1597};
    float sc[NF];
#pragma unroll
    for (int f = 0; f < NF; ++f) {
        const bool ok = (fib[f] <= s);
        const int sk = ok ? s - fib[f] : s;        // clamped, in-bounds
        const bf16x8* p = (const bf16x8*)(Kp + ((size_t)sk << 6) + c * 16);
        bf16x8 lo = p[0], hi = p[1];
        float part = 0.f;
#pragma unroll
        for (int e = 0; e < 8; ++e)
            part += qv[e] * bf2f(lo[e]) + qv[8 + e] * bf2f(hi[e]);
        part += __shfl_xor(part, 1, 64);
        part += __shfl_xor(part, 2, 64);
        sc[f] = ok ? part * 0.125f : -1e30f;
    }

    float mx = sc[0];
#pragma unroll
    for (int f = 1; f < NF; ++f) mx = fmaxf(mx, sc[f]);
    float den = 0.f;
#pragma unroll
    for (int f = 0; f < NF; ++f) { sc[f] = __expf(sc[f] - mx); den += sc[f]; }

    float o[16];
#pragma unroll
    for (int e = 0; e < 16; ++e) o[e] = 0.f;
#pragma unroll
    for (int f = 0; f < NF; ++f) {
        const int sk = (fib[f] <= s) ? s - fib[f] : s;
        const bf16x8* p = (const bf16x8*)(Vp + ((size_t)sk << 6) + c * 16);
        bf16x8 lo = p[0], hi = p[1];
        const float w = sc[f];
#pragma unroll
        for (int e = 0; e < 8; ++e) {
            o[e]     += w * bf2f(lo[e]);
            o[8 + e] += w * bf2f(hi[e]);
        }
    }

    const float inv = 1.f / den;
    short8 r0, r1;
#pragma unroll
    for (int e = 0; e < 8; ++e) {
        r0[e] = f2bf(o[e] * inv);
        r1[e] = f2bf(o[8 + e] * inv);
    }
    short* op = attn + (size_t)(b * SS + s) * DIM + h * HD + c * 16;
    ((short8*)op)[0] = r0;
    ((short8*)op)[1] = r1;
}

extern "C" void kernel_launch(void* const* d_in, const int* in_sizes, int n_in,
                              void* d_out, int out_size, void* d_ws, size_t ws_size,
                              hipStream_t stream)
{
    const float* x     = (const float*)d_in[0];
    const float* w_qkv = (const float*)d_in[1];
    const float* b_qkv = (const float*)d_in[2];
    const float* w_out = (const float*)d_in[3];
    const float* b_out = (const float*)d_in[4];
    float* out = (float*)d_out;

    // workspace (36.2 MB):
    short* qkvh  = (short*)d_ws;                              // [3][2][12][2048][64] bf16
    short* attnb = (short*)((char*)d_ws + 18874368);          // [4096][768] bf16
    short* xb    = (short*)((char*)d_ws + 25165824);          // [4096][768] bf16
    short* wqkvb = (short*)((char*)d_ws + 31457280);          // [2304][768] bf16
    short* woutb = (short*)((char*)d_ws + 34996224);          // [768][768]  bf16

    dim3 blk(256, 1, 1);

    conv_kernel<<<dim3(2688, 1, 1), blk, 0, stream>>>(x, xb, w_qkv, wqkvb, w_out, woutb);

    gemm_qkv_kernel<<<dim3(QKVN / 128, MM / 128, 1), blk, 0, stream>>>(
        xb, wqkvb, b_qkv, qkvh);

    fib_attn_kernel<<<dim3(768, 1, 1), blk, 0, stream>>>(qkvh, attnb);

    gemm_bt_bf16_kernel<<<dim3(DIM / 128, MM / 128, 1), blk, 0, stream>>>(
        attnb, woutb, b_out, out, MM, DIM, DIM);
}

// Round 6
// 72.810 us; speedup vs baseline: 3.3226x; 1.0480x over previous
//
#include <hip/hip_runtime.h>
#include <hip/hip_bf16.h>

#define DIM   768
#define NH    12
#define HD    64
#define BB    2
#define SS    2048
#define QKVN  (3 * DIM)   // 2304
#define MM    (BB * SS)   // 4096

typedef __attribute__((ext_vector_type(8))) short bf16x8;
typedef __attribute__((ext_vector_type(8))) short short8;
typedef __attribute__((ext_vector_type(4))) float f32x4;

__device__ __forceinline__ short f2bf(float f) {
    unsigned int u = __float_as_uint(f);
    unsigned int r = (u + 0x7FFFu + ((u >> 16) & 1u)) >> 16;
    return (short)r;
}
__device__ __forceinline__ float bf2f(short s) {
    return __uint_as_float((unsigned int)(unsigned short)s << 16);
}

__device__ __forceinline__ void gld16(const short* g, short* l) {
    __builtin_amdgcn_global_load_lds(
        (const __attribute__((address_space(1))) void*)g,
        (__attribute__((address_space(3))) void*)l, 16, 0, 0);
}

// fp32 -> bf16 conversion for x, w_qkv, w_out
__global__ __launch_bounds__(256) void conv_kernel(
    const float* __restrict__ x,  short* __restrict__ xb,
    const float* __restrict__ wq, short* __restrict__ wqb,
    const float* __restrict__ wo, short* __restrict__ wob)
{
    const int nx = (MM * DIM) / 8;
    const int nq = (QKVN * DIM) / 8;
    int i8 = blockIdx.x * 256 + threadIdx.x;
    const float* src; short* dst;
    if (i8 < nx)           { src = x;  dst = xb; }
    else if (i8 < nx + nq) { i8 -= nx; src = wq; dst = wqb; }
    else                   { i8 -= nx + nq; src = wo; dst = wob; }
    const float4* p = (const float4*)src + (size_t)i8 * 2;
    float4 a = p[0], b = p[1];
    short8 r;
    r[0] = f2bf(a.x); r[1] = f2bf(a.y); r[2] = f2bf(a.z); r[3] = f2bf(a.w);
    r[4] = f2bf(b.x); r[5] = f2bf(b.y); r[6] = f2bf(b.z); r[7] = f2bf(b.w);
    *((short8*)dst + i8) = r;
}

// ---------------- GEMM core (BK=64, XOR-swizzled LDS) ----------------
// LDS row-major [128][64] bf16, byte-swizzle: colbyte ^= (row&7)<<4.
// Rule #21: linear global_load_lds dest + pre-swizzled global SOURCE col +
// the same XOR on the ds_read address (involution).
// Per K-step (64): 8 gld_lds, barrier, 16 swz ds_read_b128, 32 MFMA, barrier.
__device__ __forceinline__ void gemm_core(
    const short* __restrict__ A, const short* __restrict__ Bm, int K,
    int row0, int col0, short* lsA, short* lsB, f32x4 acc[4][4])
{
    const int t    = threadIdx.x;
    const int lane = t & 63;
    const int wid  = t >> 6;
    const int wr = wid >> 1, wc = wid & 1;
    const int l16  = lane & 15;
    const int kg   = lane >> 4;

    const int srow = t >> 3;                      // 0..31
    const int scol = ((t & 7) ^ (srow & 7)) * 8;  // pre-swizzled source col
    const short* Ab = A  + (size_t)(row0 + srow) * K + scol;
    const short* Bb = Bm + (size_t)(col0 + srow) * K + scol;
    short* ldA = lsA + t * 8;
    short* ldB = lsB + t * 8;

#pragma unroll
    for (int i = 0; i < 4; ++i)
#pragma unroll
        for (int j = 0; j < 4; ++j) acc[i][j] = (f32x4){0.f, 0.f, 0.f, 0.f};

    const int sw = (l16 & 7) * 8;
    for (int k0 = 0; k0 < K; k0 += 64) {
#pragma unroll
        for (int i = 0; i < 4; ++i) {
            gld16(Ab + (size_t)(32 * i) * K + k0, ldA + i * 2048);
            gld16(Bb + (size_t)(32 * i) * K + k0, ldB + i * 2048);
        }
        __syncthreads();
#pragma unroll
        for (int kk = 0; kk < 2; ++kk) {
            bf16x8 af[4], bfr[4];
            const int ko = (kk * 32 + kg * 8) ^ sw;
#pragma unroll
            for (int i = 0; i < 4; ++i)
                af[i] = *(const bf16x8*)&lsA[(wr * 64 + i * 16 + l16) * 64 + ko];
#pragma unroll
            for (int j = 0; j < 4; ++j)
                bfr[j] = *(const bf16x8*)&lsB[(wc * 64 + j * 16 + l16) * 64 + ko];
#pragma unroll
            for (int i = 0; i < 4; ++i)
#pragma unroll
                for (int j = 0; j < 4; ++j)
                    acc[i][j] = __builtin_amdgcn_mfma_f32_16x16x32_bf16(
                        af[i], bfr[j], acc[i][j], 0, 0, 0);
        }
        __syncthreads();
    }
}

// GEMM1: qkvh[type][b][h][s][d] bf16 head-split epilogue
__global__ __launch_bounds__(256) void gemm_qkv_kernel(
    const short* __restrict__ A, const short* __restrict__ Bm,
    const float* __restrict__ bias, short* __restrict__ qkvh)
{
    __shared__ short lsA[128 * 64];
    __shared__ short lsB[128 * 64];
    f32x4 acc[4][4];
    const int row0 = blockIdx.y * 128;
    const int col0 = blockIdx.x * 128;
    gemm_core(A, Bm, DIM, row0, col0, lsA, lsB, acc);

    const int lane = threadIdx.x & 63;
    const int wid  = threadIdx.x >> 6;
    const int wr = wid >> 1, wc = wid & 1;
    const int l16 = lane & 15, kg = lane >> 4;
#pragma unroll
    for (int j = 0; j < 4; ++j) {
        const int col = col0 + wc * 64 + j * 16 + l16;
        const int ty = col / DIM;
        const int hh = (col % DIM) >> 6;
        const int dd = col & 63;
        const float bv = bias[col];
        const size_t cbase = ((size_t)(ty * BB * NH) * SS) * HD;
#pragma unroll
        for (int i = 0; i < 4; ++i) {
            const int rbase = row0 + wr * 64 + i * 16 + kg * 4;
#pragma unroll
            for (int r = 0; r < 4; ++r) {
                const int row = rbase + r;
                const int bq = row >> 11, sq = row & 2047;
                qkvh[cbase + (((size_t)(bq * NH + hh) * SS + sq) << 6) + dd] =
                    f2bf(acc[i][j][r] + bv);
            }
        }
    }
}

// GEMM2: C fp32 row-major epilogue
__global__ __launch_bounds__(256) void gemm_bt_bf16_kernel(
    const short* __restrict__ A, const short* __restrict__ Bm,
    const float* __restrict__ bias, float* __restrict__ C,
    int M, int N, int K)
{
    __shared__ short lsA[128 * 64];
    __shared__ short lsB[128 * 64];
    f32x4 acc[4][4];
    const int row0 = blockIdx.y * 128;
    const int col0 = blockIdx.x * 128;
    gemm_core(A, Bm, K, row0, col0, lsA, lsB, acc);

    const int lane = threadIdx.x & 63;
    const int wid  = threadIdx.x >> 6;
    const int wr = wid >> 1, wc = wid & 1;
    const int l16 = lane & 15, kg = lane >> 4;
#pragma unroll
    for (int j = 0; j < 4; ++j) {
        const int col = col0 + wc * 64 + j * 16 + l16;
        const float bv = bias[col];
#pragma unroll
        for (int i = 0; i < 4; ++i) {
            const int rbase = row0 + wr * 64 + i * 16 + kg * 4;
#pragma unroll
            for (int r = 0; r < 4; ++r)
                C[(size_t)(rbase + r) * N + col] = acc[i][j][r] + bv;
        }
    }
}

// Sparse Fibonacci attention, wave = 8 queries, 8 lanes/query.
// lane = (ql = lane>>3, c = lane&7); lane owns d-slice c*8..c*8+8 (one b128).
// Per K/V row: 8 lanes read 128B contiguous. Reduce = 3-step shfl_xor.
// Block = 4 waves = 32 q of one (b,h); 1536 blocks XCD-pinned.
__global__ __launch_bounds__(256) void fib_attn_kernel(
    const short* __restrict__ qkvh, short* __restrict__ attn)
{
    const int idx   = blockIdx.x;          // [0,1536)
    const int j     = idx >> 3;            // [0,192)
    const int bh    = (idx & 7) + 8 * (j >> 6);   // [0,24), pinned per XCD
    const int chunk = j & 63;              // [0,64)
    const int wid   = threadIdx.x >> 6;
    const int lane  = threadIdx.x & 63;
    const int ql    = lane >> 3;
    const int c     = lane & 7;
    const int s     = chunk * 32 + wid * 8 + ql;
    const int b = bh / NH, h = bh % NH;

    constexpr size_t TYB = (size_t)BB * NH * SS * HD;
    const size_t base = ((size_t)bh * SS) << 6;
    const short* Kp = qkvh + TYB + base;
    const short* Vp = qkvh + 2 * TYB + base;

    float qv[8];
    {
        bf16x8 v = *(const bf16x8*)(qkvh + base + ((size_t)s << 6) + c * 8);
#pragma unroll
        for (int e = 0; e < 8; ++e) qv[e] = bf2f(v[e]);
    }

    constexpr int NF = 17;
    const int fib[NF] = {0, 1, 2, 3, 5, 8, 13, 21, 34, 55, 89, 144,
                         233, 377, 610, 987, 1597};
    float sc[NF];
#pragma unroll
    for (int f = 0; f < NF; ++f) {
        const bool ok = (fib[f] <= s);
        const int sk = ok ? s - fib[f] : s;        // clamped, in-bounds
        bf16x8 kv = *(const bf16x8*)(Kp + ((size_t)sk << 6) + c * 8);
        float part = 0.f;
#pragma unroll
        for (int e = 0; e < 8; ++e) part += qv[e] * bf2f(kv[e]);
        part += __shfl_xor(part, 1, 64);
        part += __shfl_xor(part, 2, 64);
        part += __shfl_xor(part, 4, 64);
        sc[f] = ok ? part * 0.125f : -1e30f;
    }

    float mx = sc[0];
#pragma unroll
    for (int f = 1; f < NF; ++f) mx = fmaxf(mx, sc[f]);
    float den = 0.f;
#pragma unroll
    for (int f = 0; f < NF; ++f) { sc[f] = __expf(sc[f] - mx); den += sc[f]; }

    float o[8];
#pragma unroll
    for (int e = 0; e < 8; ++e) o[e] = 0.f;
#pragma unroll
    for (int f = 0; f < NF; ++f) {
        const int sk = (fib[f] <= s) ? s - fib[f] : s;
        bf16x8 vv = *(const bf16x8*)(Vp + ((size_t)sk << 6) + c * 8);
        const float w = sc[f];
#pragma unroll
        for (int e = 0; e < 8; ++e) o[e] += w * bf2f(vv[e]);
    }

    const float inv = 1.f / den;
    short8 r;
#pragma unroll
    for (int e = 0; e < 8; ++e) r[e] = f2bf(o[e] * inv);
    *(short8*)(attn + (size_t)(b * SS + s) * DIM + h * HD + c * 8) = r;
}

extern "C" void kernel_launch(void* const* d_in, const int* in_sizes, int n_in,
                              void* d_out, int out_size, void* d_ws, size_t ws_size,
                              hipStream_t stream)
{
    const float* x     = (const float*)d_in[0];
    const float* w_qkv = (const float*)d_in[1];
    const float* b_qkv = (const float*)d_in[2];
    const float* w_out = (const float*)d_in[3];
    const float* b_out = (const float*)d_in[4];
    float* out = (float*)d_out;

    short* qkvh  = (short*)d_ws;                              // [3][2][12][2048][64] bf16
    short* attnb = (short*)((char*)d_ws + 18874368);          // [4096][768] bf16
    short* xb    = (short*)((char*)d_ws + 25165824);          // [4096][768] bf16
    short* wqkvb = (short*)((char*)d_ws + 31457280);          // [2304][768] bf16
    short* woutb = (short*)((char*)d_ws + 34996224);          // [768][768]  bf16

    dim3 blk(256, 1, 1);

    conv_kernel<<<dim3(2688, 1, 1), blk, 0, stream>>>(x, xb, w_qkv, wqkvb, w_out, woutb);

    gemm_qkv_kernel<<<dim3(QKVN / 128, MM / 128, 1), blk, 0, stream>>>(
        xb, wqkvb, b_qkv, qkvh);

    fib_attn_kernel<<<dim3(1536, 1, 1), blk, 0, stream>>>(qkvh, attnb);

    gemm_bt_bf16_kernel<<<dim3(DIM / 128, MM / 128, 1), blk, 0, stream>>>(
        attnb, woutb, b_out, out, MM, DIM, DIM);
}

// Round 7
// 69.259 us; speedup vs baseline: 3.4930x; 1.0513x over previous
//
#include <hip/hip_runtime.h>
#include <hip/hip_bf16.h>

#define DIM   768
#define NH    12
#define HD    64
#define BB    2
#define SS    2048
#define QKVN  (3 * DIM)   // 2304
#define MM    (BB * SS)   // 4096

typedef __attribute__((ext_vector_type(8))) short bf16x8;
typedef __attribute__((ext_vector_type(8))) short short8;
typedef __attribute__((ext_vector_type(4))) float f32x4;

__device__ __forceinline__ short f2bf(float f) {
    unsigned int u = __float_as_uint(f);
    unsigned int r = (u + 0x7FFFu + ((u >> 16) & 1u)) >> 16;
    return (short)r;
}
__device__ __forceinline__ float bf2f(short s) {
    return __uint_as_float((unsigned int)(unsigned short)s << 16);
}

__device__ __forceinline__ void gld16(const short* g, short* l) {
    __builtin_amdgcn_global_load_lds(
        (const __attribute__((address_space(1))) void*)g,
        (__attribute__((address_space(3))) void*)l, 16, 0, 0);
}

// fp32 -> bf16 conversion for x, w_qkv, w_out
__global__ __launch_bounds__(256) void conv_kernel(
    const float* __restrict__ x,  short* __restrict__ xb,
    const float* __restrict__ wq, short* __restrict__ wqb,
    const float* __restrict__ wo, short* __restrict__ wob)
{
    const int nx = (MM * DIM) / 8;
    const int nq = (QKVN * DIM) / 8;
    int i8 = blockIdx.x * 256 + threadIdx.x;
    const float* src; short* dst;
    if (i8 < nx)           { src = x;  dst = xb; }
    else if (i8 < nx + nq) { i8 -= nx; src = wq; dst = wqb; }
    else                   { i8 -= nx + nq; src = wo; dst = wob; }
    const float4* p = (const float4*)src + (size_t)i8 * 2;
    float4 a = p[0], b = p[1];
    short8 r;
    r[0] = f2bf(a.x); r[1] = f2bf(a.y); r[2] = f2bf(a.z); r[3] = f2bf(a.w);
    r[4] = f2bf(b.x); r[5] = f2bf(b.y); r[6] = f2bf(b.z); r[7] = f2bf(b.w);
    *((short8*)dst + i8) = r;
}

// ------------- GEMM core: 512 thr (8 waves 2x4), BK=64, dbuf LDS -------------
// T3-minimum 2-phase: STAGE(next) issued BEFORE compute(current); one
// __syncthreads (vmcnt(0)+barrier) AFTER compute. LDS [R][64] bf16 with
// rule-#21 XOR swizzle (pre-swizzled global source col, swz ds_read).
// Wave (wrow=wid>>2, wcol=wid&3) owns (MF*16) x (NF*16) of the C tile.

template<int RT>   // RT = tile rows (BM or BN), issues = RT/64
__device__ __forceinline__ void stage_op(const short* gb, int K, int k0, short* ld)
{
#pragma unroll
    for (int ii = 0; ii < RT / 64; ++ii)
        gld16(gb + (size_t)(64 * ii) * K + k0, ld + ii * 4096);
}

template<int MF, int NF>
__device__ __forceinline__ void compute_tile(
    const short* lsA, const short* lsB, int arow, int brow, int kg, int sw,
    f32x4 acc[MF][NF])
{
#pragma unroll
    for (int kk = 0; kk < 2; ++kk) {
        const int ko = (kk * 32 + kg * 8) ^ sw;
        bf16x8 af[MF], bfr[NF];
#pragma unroll
        for (int i = 0; i < MF; ++i)
            af[i] = *(const bf16x8*)&lsA[(arow + i * 16) * 64 + ko];
#pragma unroll
        for (int j = 0; j < NF; ++j)
            bfr[j] = *(const bf16x8*)&lsB[(brow + j * 16) * 64 + ko];
#pragma unroll
        for (int i = 0; i < MF; ++i)
#pragma unroll
            for (int j = 0; j < NF; ++j)
                acc[i][j] = __builtin_amdgcn_mfma_f32_16x16x32_bf16(
                    af[i], bfr[j], acc[i][j], 0, 0, 0);
    }
}

// GEMM1: BM=128, BN=128, MF=4, NF=2. qkvh[type][b][h][s][d] bf16 epilogue.
__global__ __launch_bounds__(512) void gemm_qkv_kernel(
    const short* __restrict__ A, const short* __restrict__ Bm,
    const float* __restrict__ bias, short* __restrict__ qkvh)
{
    constexpr int K = DIM;
    __shared__ short lsA0[8192], lsB0[8192], lsA1[8192], lsB1[8192];

    const int t    = threadIdx.x;
    const int lane = t & 63;
    const int wid  = t >> 6;
    const int wrow = wid >> 2, wcol = wid & 3;
    const int l16  = lane & 15;
    const int kg   = lane >> 4;
    const int row0 = blockIdx.y * 128;
    const int col0 = blockIdx.x * 128;

    const int srow = t >> 3;
    const int scol = ((t & 7) ^ (srow & 7)) * 8;
    const short* Ab = A  + (size_t)(row0 + srow) * K + scol;
    const short* Bb = Bm + (size_t)(col0 + srow) * K + scol;
    short* ldA0 = lsA0 + t * 8;  short* ldB0 = lsB0 + t * 8;
    short* ldA1 = lsA1 + t * 8;  short* ldB1 = lsB1 + t * 8;
    const int arow = wrow * 64 + l16;
    const int brow = wcol * 32 + l16;
    const int sw   = (l16 & 7) * 8;

    f32x4 acc[4][2];
#pragma unroll
    for (int i = 0; i < 4; ++i)
#pragma unroll
        for (int j = 0; j < 2; ++j) acc[i][j] = (f32x4){0.f, 0.f, 0.f, 0.f};

    constexpr int NT = K / 64;   // 12 (even)
    stage_op<128>(Ab, K, 0, ldA0);
    stage_op<128>(Bb, K, 0, ldB0);
    __syncthreads();
    for (int kt = 0; kt < NT; kt += 2) {
        stage_op<128>(Ab, K, (kt + 1) * 64, ldA1);
        stage_op<128>(Bb, K, (kt + 1) * 64, ldB1);
        compute_tile<4, 2>(lsA0, lsB0, arow, brow, kg, sw, acc);
        __syncthreads();
        if (kt + 2 < NT) {
            stage_op<128>(Ab, K, (kt + 2) * 64, ldA0);
            stage_op<128>(Bb, K, (kt + 2) * 64, ldB0);
        }
        compute_tile<4, 2>(lsA1, lsB1, arow, brow, kg, sw, acc);
        __syncthreads();
    }

#pragma unroll
    for (int j = 0; j < 2; ++j) {
        const int col = col0 + wcol * 32 + j * 16 + l16;
        const int ty = col / DIM;
        const int hh = (col % DIM) >> 6;
        const int dd = col & 63;
        const float bv = bias[col];
        const size_t cbase = ((size_t)(ty * BB * NH) * SS) * HD;
#pragma unroll
        for (int i = 0; i < 4; ++i) {
            const int rbase = row0 + wrow * 64 + i * 16 + kg * 4;
#pragma unroll
            for (int r = 0; r < 4; ++r) {
                const int row = rbase + r;
                const int bq = row >> 11, sq = row & 2047;
                qkvh[cbase + (((size_t)(bq * NH + hh) * SS + sq) << 6) + dd] =
                    f2bf(acc[i][j][r] + bv);
            }
        }
    }
}

// GEMM2: BM=64, BN=128, MF=2, NF=2 (grid 64x6=384 blocks). C fp32 epilogue.
__global__ __launch_bounds__(512) void gemm_out_kernel(
    const short* __restrict__ A, const short* __restrict__ Bm,
    const float* __restrict__ bias, float* __restrict__ C)
{
    constexpr int K = DIM, N = DIM;
    __shared__ short lsA0[4096], lsB0[8192], lsA1[4096], lsB1[8192];

    const int t    = threadIdx.x;
    const int lane = t & 63;
    const int wid  = t >> 6;
    const int wrow = wid >> 2, wcol = wid & 3;
    const int l16  = lane & 15;
    const int kg   = lane >> 4;
    const int row0 = blockIdx.y * 64;
    const int col0 = blockIdx.x * 128;

    const int srow = t >> 3;
    const int scol = ((t & 7) ^ (srow & 7)) * 8;
    const short* Ab = A  + (size_t)(row0 + srow) * K + scol;
    const short* Bb = Bm + (size_t)(col0 + srow) * K + scol;
    short* ldA0 = lsA0 + t * 8;  short* ldB0 = lsB0 + t * 8;
    short* ldA1 = lsA1 + t * 8;  short* ldB1 = lsB1 + t * 8;
    const int arow = wrow * 32 + l16;
    const int brow = wcol * 32 + l16;
    const int sw   = (l16 & 7) * 8;

    f32x4 acc[2][2];
#pragma unroll
    for (int i = 0; i < 2; ++i)
#pragma unroll
        for (int j = 0; j < 2; ++j) acc[i][j] = (f32x4){0.f, 0.f, 0.f, 0.f};

    constexpr int NT = K / 64;   // 12
    stage_op<64>(Ab, K, 0, ldA0);
    stage_op<128>(Bb, K, 0, ldB0);
    __syncthreads();
    for (int kt = 0; kt < NT; kt += 2) {
        stage_op<64>(Ab, K, (kt + 1) * 64, ldA1);
        stage_op<128>(Bb, K, (kt + 1) * 64, ldB1);
        compute_tile<2, 2>(lsA0, lsB0, arow, brow, kg, sw, acc);
        __syncthreads();
        if (kt + 2 < NT) {
            stage_op<64>(Ab, K, (kt + 2) * 64, ldA0);
            stage_op<128>(Bb, K, (kt + 2) * 64, ldB0);
        }
        compute_tile<2, 2>(lsA1, lsB1, arow, brow, kg, sw, acc);
        __syncthreads();
    }

#pragma unroll
    for (int j = 0; j < 2; ++j) {
        const int col = col0 + wcol * 32 + j * 16 + l16;
        const float bv = bias[col];
#pragma unroll
        for (int i = 0; i < 2; ++i) {
            const int rbase = row0 + wrow * 32 + i * 16 + kg * 4;
#pragma unroll
            for (int r = 0; r < 4; ++r)
                C[(size_t)(rbase + r) * N + col] = acc[i][j][r] + bv;
        }
    }
}

// Sparse Fibonacci attention, wave = 8 queries, 8 lanes/query (unchanged).
__global__ __launch_bounds__(256) void fib_attn_kernel(
    const short* __restrict__ qkvh, short* __restrict__ attn)
{
    const int idx   = blockIdx.x;          // [0,1536)
    const int j     = idx >> 3;            // [0,192)
    const int bh    = (idx & 7) + 8 * (j >> 6);   // [0,24), pinned per XCD
    const int chunk = j & 63;              // [0,64)
    const int wid   = threadIdx.x >> 6;
    const int lane  = threadIdx.x & 63;
    const int ql    = lane >> 3;
    const int c     = lane & 7;
    const int s     = chunk * 32 + wid * 8 + ql;
    const int b = bh / NH, h = bh % NH;

    constexpr size_t TYB = (size_t)BB * NH * SS * HD;
    const size_t base = ((size_t)bh * SS) << 6;
    const short* Kp = qkvh + TYB + base;
    const short* Vp = qkvh + 2 * TYB + base;

    float qv[8];
    {
        bf16x8 v = *(const bf16x8*)(qkvh + base + ((size_t)s << 6) + c * 8);
#pragma unroll
        for (int e = 0; e < 8; ++e) qv[e] = bf2f(v[e]);
    }

    constexpr int NF = 17;
    const int fib[NF] = {0, 1, 2, 3, 5, 8, 13, 21, 34, 55, 89, 144,
                         233, 377, 610, 987, 1597};
    float sc[NF];
#pragma unroll
    for (int f = 0; f < NF; ++f) {
        const bool ok = (fib[f] <= s);
        const int sk = ok ? s - fib[f] : s;
        bf16x8 kv = *(const bf16x8*)(Kp + ((size_t)sk << 6) + c * 8);
        float part = 0.f;
#pragma unroll
        for (int e = 0; e < 8; ++e) part += qv[e] * bf2f(kv[e]);
        part += __shfl_xor(part, 1, 64);
        part += __shfl_xor(part, 2, 64);
        part += __shfl_xor(part, 4, 64);
        sc[f] = ok ? part * 0.125f : -1e30f;
    }

    float mx = sc[0];
#pragma unroll
    for (int f = 1; f < NF; ++f) mx = fmaxf(mx, sc[f]);
    float den = 0.f;
#pragma unroll
    for (int f = 0; f < NF; ++f) { sc[f] = __expf(sc[f] - mx); den += sc[f]; }

    float o[8];
#pragma unroll
    for (int e = 0; e < 8; ++e) o[e] = 0.f;
#pragma unroll
    for (int f = 0; f < NF; ++f) {
        const int sk = (fib[f] <= s) ? s - fib[f] : s;
        bf16x8 vv = *(const bf16x8*)(Vp + ((size_t)sk << 6) + c * 8);
        const float w = sc[f];
#pragma unroll
        for (int e = 0; e < 8; ++e) o[e] += w * bf2f(vv[e]);
    }

    const float inv = 1.f / den;
    short8 r;
#pragma unroll
    for (int e = 0; e < 8; ++e) r[e] = f2bf(o[e] * inv);
    *(short8*)(attn + (size_t)(b * SS + s) * DIM + h * HD + c * 8) = r;
}

extern "C" void kernel_launch(void* const* d_in, const int* in_sizes, int n_in,
                              void* d_out, int out_size, void* d_ws, size_t ws_size,
                              hipStream_t stream)
{
    const float* x     = (const float*)d_in[0];
    const float* w_qkv = (const float*)d_in[1];
    const float* b_qkv = (const float*)d_in[2];
    const float* w_out = (const float*)d_in[3];
    const float* b_out = (const float*)d_in[4];
    float* out = (float*)d_out;

    short* qkvh  = (short*)d_ws;                              // [3][2][12][2048][64] bf16
    short* attnb = (short*)((char*)d_ws + 18874368);          // [4096][768] bf16
    short* xb    = (short*)((char*)d_ws + 25165824);          // [4096][768] bf16
    short* wqkvb = (short*)((char*)d_ws + 31457280);          // [2304][768] bf16
    short* woutb = (short*)((char*)d_ws + 34996224);          // [768][768]  bf16

    conv_kernel<<<dim3(2688, 1, 1), dim3(256, 1, 1), 0, stream>>>(
        x, xb, w_qkv, wqkvb, w_out, woutb);

    gemm_qkv_kernel<<<dim3(QKVN / 128, MM / 128, 1), dim3(512, 1, 1), 0, stream>>>(
        xb, wqkvb, b_qkv, qkvh);

    fib_attn_kernel<<<dim3(1536, 1, 1), dim3(256, 1, 1), 0, stream>>>(qkvh, attnb);

    gemm_out_kernel<<<dim3(DIM / 128, MM / 64, 1), dim3(512, 1, 1), 0, stream>>>(
        attnb, woutb, b_out, out);
}

// Round 8
// 59.469 us; speedup vs baseline: 4.0681x; 1.1646x over previous
//
#include <hip/hip_runtime.h>
#include <hip/hip_bf16.h>

#define DIM   768
#define NH    12
#define HD    64
#define BB    2
#define SS    2048
#define QKVN  (3 * DIM)   // 2304
#define MM    (BB * SS)   // 4096

typedef __attribute__((ext_vector_type(8))) short bf16x8;
typedef __attribute__((ext_vector_type(8))) short short8;
typedef __attribute__((ext_vector_type(4))) float f32x4;

__device__ __forceinline__ short f2bf(float f) {
    unsigned int u = __float_as_uint(f);
    unsigned int r = (u + 0x7FFFu + ((u >> 16) & 1u)) >> 16;
    return (short)r;
}
__device__ __forceinline__ float bf2f(short s) {
    return __uint_as_float((unsigned int)(unsigned short)s << 16);
}

__device__ __forceinline__ void gld16(const short* g, short* l) {
    __builtin_amdgcn_global_load_lds(
        (const __attribute__((address_space(1))) void*)g,
        (__attribute__((address_space(3))) void*)l, 16, 0, 0);
}

template<int N> __device__ __forceinline__ void waitvm() {
    if constexpr (N == 0) asm volatile("s_waitcnt vmcnt(0)" ::: "memory");
    else if constexpr (N == 3) asm volatile("s_waitcnt vmcnt(3)" ::: "memory");
    else if constexpr (N == 4) asm volatile("s_waitcnt vmcnt(4)" ::: "memory");
}

// fp32 -> bf16 conversion for x, w_qkv, w_out
__global__ __launch_bounds__(256) void conv_kernel(
    const float* __restrict__ x,  short* __restrict__ xb,
    const float* __restrict__ wq, short* __restrict__ wqb,
    const float* __restrict__ wo, short* __restrict__ wob)
{
    const int nx = (MM * DIM) / 8;
    const int nq = (QKVN * DIM) / 8;
    int i8 = blockIdx.x * 256 + threadIdx.x;
    const float* src; short* dst;
    if (i8 < nx)           { src = x;  dst = xb; }
    else if (i8 < nx + nq) { i8 -= nx; src = wq; dst = wqb; }
    else                   { i8 -= nx + nq; src = wo; dst = wob; }
    const float4* p = (const float4*)src + (size_t)i8 * 2;
    float4 a = p[0], b = p[1];
    short8 r;
    r[0] = f2bf(a.x); r[1] = f2bf(a.y); r[2] = f2bf(a.z); r[3] = f2bf(a.w);
    r[4] = f2bf(b.x); r[5] = f2bf(b.y); r[6] = f2bf(b.z); r[7] = f2bf(b.w);
    *((short8*)dst + i8) = r;
}

// ------------- GEMM core: counted-vmcnt 2-buffer pipeline -------------
// LDS [R][64] bf16, rule-#21 XOR swizzle. Per tile phase:
//   ds_read frags ; lgkmcnt(0) ; barrier        (all reads retired)
//   stage(cur buf, t+2)                          (overwrite-safe, async)
//   MFMA ; vmcnt(VC) ; barrier                   (next tile landed; t+2 in flight)

template<int RT>   // RT = tile rows; issues = RT/64 per operand
__device__ __forceinline__ void stage_op(const short* gb, int K, int k0, short* ld)
{
#pragma unroll
    for (int ii = 0; ii < RT / 64; ++ii)
        gld16(gb + (size_t)(64 * ii) * K + k0, ld + ii * 4096);
}

template<int MF, int NF>
__device__ __forceinline__ void read_frags(
    const short* lsA, const short* lsB, int arow, int brow, int kg, int sw,
    bf16x8 af[2][MF], bf16x8 bfr[2][NF])
{
#pragma unroll
    for (int kk = 0; kk < 2; ++kk) {
        const int ko = (kk * 32 + kg * 8) ^ sw;
#pragma unroll
        for (int i = 0; i < MF; ++i)
            af[kk][i] = *(const bf16x8*)&lsA[(arow + i * 16) * 64 + ko];
#pragma unroll
        for (int j = 0; j < NF; ++j)
            bfr[kk][j] = *(const bf16x8*)&lsB[(brow + j * 16) * 64 + ko];
    }
}

template<int MF, int NF>
__device__ __forceinline__ void mfma_frags(
    bf16x8 af[2][MF], bf16x8 bfr[2][NF], f32x4 acc[MF][NF])
{
#pragma unroll
    for (int kk = 0; kk < 2; ++kk)
#pragma unroll
        for (int i = 0; i < MF; ++i)
#pragma unroll
            for (int j = 0; j < NF; ++j)
                acc[i][j] = __builtin_amdgcn_mfma_f32_16x16x32_bf16(
                    af[kk][i], bfr[kk][j], acc[i][j], 0, 0, 0);
}

// One steady-state phase: compute tile in (lsA,lsB), stage k_next into same bufs.
template<int MF, int NF, int ART, int BRT, int VC>
__device__ __forceinline__ void phase_steady(
    const short* lsA, const short* lsB, short* ldA, short* ldB,
    const short* Ab, const short* Bb, int K, int knext,
    int arow, int brow, int kg, int sw, f32x4 acc[MF][NF])
{
    bf16x8 af[2][MF], bfr[2][NF];
    read_frags<MF, NF>(lsA, lsB, arow, brow, kg, sw, af, bfr);
    asm volatile("s_waitcnt lgkmcnt(0)" ::: "memory");
    __builtin_amdgcn_s_barrier();
    stage_op<ART>(Ab, K, knext, ldA);
    stage_op<BRT>(Bb, K, knext, ldB);
    mfma_frags<MF, NF>(af, bfr, acc);
    waitvm<VC>();
    __builtin_amdgcn_s_barrier();
}

// GEMM1: BM=128, BN=128, 512 thr (8 waves 2x4), MF=4, NF=2. K=768 (NT=12).
__global__ __launch_bounds__(512) void gemm_qkv_kernel(
    const short* __restrict__ A, const short* __restrict__ Bm,
    const float* __restrict__ bias, short* __restrict__ qkvh)
{
    constexpr int K = DIM, NT = 12;
    __shared__ short lsA0[8192], lsB0[8192], lsA1[8192], lsB1[8192];

    const int t    = threadIdx.x;
    const int lane = t & 63;
    const int wid  = t >> 6;
    const int wrow = wid >> 2, wcol = wid & 3;
    const int l16  = lane & 15;
    const int kg   = lane >> 4;
    const int row0 = blockIdx.y * 128;
    const int col0 = blockIdx.x * 128;

    const int srow = t >> 3;
    const int scol = ((t & 7) ^ (srow & 7)) * 8;
    const short* Ab = A  + (size_t)(row0 + srow) * K + scol;
    const short* Bb = Bm + (size_t)(col0 + srow) * K + scol;
    short* ldA0 = lsA0 + t * 8;  short* ldB0 = lsB0 + t * 8;
    short* ldA1 = lsA1 + t * 8;  short* ldB1 = lsB1 + t * 8;
    const int arow = wrow * 64 + l16;
    const int brow = wcol * 32 + l16;
    const int sw   = (l16 & 7) * 8;

    f32x4 acc[4][2];
#pragma unroll
    for (int i = 0; i < 4; ++i)
#pragma unroll
        for (int j = 0; j < 2; ++j) acc[i][j] = (f32x4){0.f, 0.f, 0.f, 0.f};

    // prologue: tiles 0,1 -> 8 outstanding; wait tile0 (4 remain)
    stage_op<128>(Ab, K, 0, ldA0);
    stage_op<128>(Bb, K, 0, ldB0);
    stage_op<128>(Ab, K, 64, ldA1);
    stage_op<128>(Bb, K, 64, ldB1);
    waitvm<4>();
    __builtin_amdgcn_s_barrier();

#pragma unroll
    for (int kt = 0; kt < NT - 2; kt += 2) {
        phase_steady<4, 2, 128, 128, 4>(lsA0, lsB0, ldA0, ldB0, Ab, Bb, K,
                                        (kt + 2) * 64, arow, brow, kg, sw, acc);
        phase_steady<4, 2, 128, 128, 4>(lsA1, lsB1, ldA1, ldB1, Ab, Bb, K,
                                        (kt + 3) * 64, arow, brow, kg, sw, acc);
    }
    // tail: tile NT-2 in b0 (t NT-1's loads still in flight), tile NT-1 in b1
    {
        bf16x8 af[2][4], bfr[2][2];
        read_frags<4, 2>(lsA0, lsB0, arow, brow, kg, sw, af, bfr);
        mfma_frags<4, 2>(af, bfr, acc);
        waitvm<0>();
        __builtin_amdgcn_s_barrier();
        read_frags<4, 2>(lsA1, lsB1, arow, brow, kg, sw, af, bfr);
        mfma_frags<4, 2>(af, bfr, acc);
    }

#pragma unroll
    for (int j = 0; j < 2; ++j) {
        const int col = col0 + wcol * 32 + j * 16 + l16;
        const int ty = col / DIM;
        const int hh = (col % DIM) >> 6;
        const int dd = col & 63;
        const float bv = bias[col];
        const size_t cbase = ((size_t)(ty * BB * NH) * SS) * HD;
#pragma unroll
        for (int i = 0; i < 4; ++i) {
            const int rbase = row0 + wrow * 64 + i * 16 + kg * 4;
#pragma unroll
            for (int r = 0; r < 4; ++r) {
                const int row = rbase + r;
                const int bq = row >> 11, sq = row & 2047;
                qkvh[cbase + (((size_t)(bq * NH + hh) * SS + sq) << 6) + dd] =
                    f2bf(acc[i][j][r] + bv);
            }
        }
    }
}

// GEMM2: BM=64, BN=128, 512 thr, MF=2, NF=2 (grid 6x64=384). NT=12.
__global__ __launch_bounds__(512) void gemm_out_kernel(
    const short* __restrict__ A, const short* __restrict__ Bm,
    const float* __restrict__ bias, float* __restrict__ C)
{
    constexpr int K = DIM, N = DIM, NT = 12;
    __shared__ short lsA0[4096], lsB0[8192], lsA1[4096], lsB1[8192];

    const int t    = threadIdx.x;
    const int lane = t & 63;
    const int wid  = t >> 6;
    const int wrow = wid >> 2, wcol = wid & 3;
    const int l16  = lane & 15;
    const int kg   = lane >> 4;
    const int row0 = blockIdx.y * 64;
    const int col0 = blockIdx.x * 128;

    const int srow = t >> 3;
    const int scol = ((t & 7) ^ (srow & 7)) * 8;
    const short* Ab = A  + (size_t)(row0 + srow) * K + scol;
    const short* Bb = Bm + (size_t)(col0 + srow) * K + scol;
    short* ldA0 = lsA0 + t * 8;  short* ldB0 = lsB0 + t * 8;
    short* ldA1 = lsA1 + t * 8;  short* ldB1 = lsB1 + t * 8;
    const int arow = wrow * 32 + l16;
    const int brow = wcol * 32 + l16;
    const int sw   = (l16 & 7) * 8;

    f32x4 acc[2][2];
#pragma unroll
    for (int i = 0; i < 2; ++i)
#pragma unroll
        for (int j = 0; j < 2; ++j) acc[i][j] = (f32x4){0.f, 0.f, 0.f, 0.f};

    stage_op<64>(Ab, K, 0, ldA0);
    stage_op<128>(Bb, K, 0, ldB0);
    stage_op<64>(Ab, K, 64, ldA1);
    stage_op<128>(Bb, K, 64, ldB1);
    waitvm<3>();
    __builtin_amdgcn_s_barrier();

#pragma unroll
    for (int kt = 0; kt < NT - 2; kt += 2) {
        phase_steady<2, 2, 64, 128, 3>(lsA0, lsB0, ldA0, ldB0, Ab, Bb, K,
                                       (kt + 2) * 64, arow, brow, kg, sw, acc);
        phase_steady<2, 2, 64, 128, 3>(lsA1, lsB1, ldA1, ldB1, Ab, Bb, K,
                                       (kt + 3) * 64, arow, brow, kg, sw, acc);
    }
    {
        bf16x8 af[2][2], bfr[2][2];
        read_frags<2, 2>(lsA0, lsB0, arow, brow, kg, sw, af, bfr);
        mfma_frags<2, 2>(af, bfr, acc);
        waitvm<0>();
        __builtin_amdgcn_s_barrier();
        read_frags<2, 2>(lsA1, lsB1, arow, brow, kg, sw, af, bfr);
        mfma_frags<2, 2>(af, bfr, acc);
    }

#pragma unroll
    for (int j = 0; j < 2; ++j) {
        const int col = col0 + wcol * 32 + j * 16 + l16;
        const float bv = bias[col];
#pragma unroll
        for (int i = 0; i < 2; ++i) {
            const int rbase = row0 + wrow * 32 + i * 16 + kg * 4;
#pragma unroll
            for (int r = 0; r < 4; ++r)
                C[(size_t)(rbase + r) * N + col] = acc[i][j][r] + bv;
        }
    }
}

// Sparse Fibonacci attention, wave = 8 queries, 8 lanes/query (unchanged).
__global__ __launch_bounds__(256) void fib_attn_kernel(
    const short* __restrict__ qkvh, short* __restrict__ attn)
{
    const int idx   = blockIdx.x;          // [0,1536)
    const int j     = idx >> 3;            // [0,192)
    const int bh    = (idx & 7) + 8 * (j >> 6);   // [0,24), pinned per XCD
    const int chunk = j & 63;              // [0,64)
    const int wid   = threadIdx.x >> 6;
    const int lane  = threadIdx.x & 63;
    const int ql    = lane >> 3;
    const int c     = lane & 7;
    const int s     = chunk * 32 + wid * 8 + ql;
    const int b = bh / NH, h = bh % NH;

    constexpr size_t TYB = (size_t)BB * NH * SS * HD;
    const size_t base = ((size_t)bh * SS) << 6;
    const short* Kp = qkvh + TYB + base;
    const short* Vp = qkvh + 2 * TYB + base;

    float qv[8];
    {
        bf16x8 v = *(const bf16x8*)(qkvh + base + ((size_t)s << 6) + c * 8);
#pragma unroll
        for (int e = 0; e < 8; ++e) qv[e] = bf2f(v[e]);
    }

    constexpr int NF = 17;
    const int fib[NF] = {0, 1, 2, 3, 5, 8, 13, 21, 34, 55, 89, 144,
                         233, 377, 610, 987, 1597};
    float sc[NF];
#pragma unroll
    for (int f = 0; f < NF; ++f) {
        const bool ok = (fib[f] <= s);
        const int sk = ok ? s - fib[f] : s;
        bf16x8 kv = *(const bf16x8*)(Kp + ((size_t)sk << 6) + c * 8);
        float part = 0.f;
#pragma unroll
        for (int e = 0; e < 8; ++e) part += qv[e] * bf2f(kv[e]);
        part += __shfl_xor(part, 1, 64);
        part += __shfl_xor(part, 2, 64);
        part += __shfl_xor(part, 4, 64);
        sc[f] = ok ? part * 0.125f : -1e30f;
    }

    float mx = sc[0];
#pragma unroll
    for (int f = 1; f < NF; ++f) mx = fmaxf(mx, sc[f]);
    float den = 0.f;
#pragma unroll
    for (int f = 0; f < NF; ++f) { sc[f] = __expf(sc[f] - mx); den += sc[f]; }

    float o[8];
#pragma unroll
    for (int e = 0; e < 8; ++e) o[e] = 0.f;
#pragma unroll
    for (int f = 0; f < NF; ++f) {
        const int sk = (fib[f] <= s) ? s - fib[f] : s;
        bf16x8 vv = *(const bf16x8*)(Vp + ((size_t)sk << 6) + c * 8);
        const float w = sc[f];
#pragma unroll
        for (int e = 0; e < 8; ++e) o[e] += w * bf2f(vv[e]);
    }

    const float inv = 1.f / den;
    short8 r;
#pragma unroll
    for (int e = 0; e < 8; ++e) r[e] = f2bf(o[e] * inv);
    *(short8*)(attn + (size_t)(b * SS + s) * DIM + h * HD + c * 8) = r;
}

extern "C" void kernel_launch(void* const* d_in, const int* in_sizes, int n_in,
                              void* d_out, int out_size, void* d_ws, size_t ws_size,
                              hipStream_t stream)
{
    const float* x     = (const float*)d_in[0];
    const float* w_qkv = (const float*)d_in[1];
    const float* b_qkv = (const float*)d_in[2];
    const float* w_out = (const float*)d_in[3];
    const float* b_out = (const float*)d_in[4];
    float* out = (float*)d_out;

    short* qkvh  = (short*)d_ws;                              // [3][2][12][2048][64] bf16
    short* attnb = (short*)((char*)d_ws + 18874368);          // [4096][768] bf16
    short* xb    = (short*)((char*)d_ws + 25165824);          // [4096][768] bf16
    short* wqkvb = (short*)((char*)d_ws + 31457280);          // [2304][768] bf16
    short* woutb = (short*)((char*)d_ws + 34996224);          // [768][768]  bf16

    conv_kernel<<<dim3(2688, 1, 1), dim3(256, 1, 1), 0, stream>>>(
        x, xb, w_qkv, wqkvb, w_out, woutb);

    gemm_qkv_kernel<<<dim3(QKVN / 128, MM / 128, 1), dim3(512, 1, 1), 0, stream>>>(
        xb, wqkvb, b_qkv, qkvh);

    fib_attn_kernel<<<dim3(1536, 1, 1), dim3(256, 1, 1), 0, stream>>>(qkvh, attnb);

    gemm_out_kernel<<<dim3(DIM / 128, MM / 64, 1), dim3(512, 1, 1), 0, stream>>>(
        attnb, woutb, b_out, out);
}